// Round 8
// baseline (594.337 us; speedup 1.0000x reference)
//
#include <hip/hip_runtime.h>

// Problem constants (reference: B=16, NAT=256, K=24, F=128, L=4, EPS=0.01)
#define NB 16
#define NATS 256
#define KNN 24
#define FD 128
#define EPSA 0.01f
#define NATOMS (NB * NATS)      // 4096
#define NEDGE (NATOMS * KNN)    // 98304

typedef __attribute__((ext_vector_type(8))) short short8;   // 8 bf16 (a/b frag)
typedef __attribute__((ext_vector_type(4))) float f32x4;    // C/D frag

__device__ __forceinline__ float silu_f(float v) { return v / (1.f + __expf(-v)); }

__device__ __forceinline__ short f2b(float f) {             // fp32 -> bf16 (RNE)
    union { float f; unsigned u; } v; v.f = f;
    unsigned r = v.u + 0x7FFFu + ((v.u >> 16) & 1u);
    return (short)(r >> 16);
}
__device__ __forceinline__ float b2f(short s) {
    return __uint_as_float(((unsigned)(unsigned short)s) << 16);
}
// b-frag: 16B contiguous chunk of transposed weight [n][k]
__device__ __forceinline__ short8 ldb(const short* __restrict__ W, int n, int ks, int quad) {
    return *(const short8*)&W[n * 128 + ks * 32 + quad * 8];
}

// ---------------- prep: transpose + bf16 hi/lo split of all 16 weight matrices ----------------
__global__ __launch_bounds__(256) void prep_kernel(
    const float* __restrict__ mW1, const float* __restrict__ mW2,
    const float* __restrict__ uW1, const float* __restrict__ uW2,
    short* __restrict__ wh, short* __restrict__ wl_)
{
    int tid = blockIdx.x * 256 + threadIdx.x;   // 1024*256 = 262144 = 16*16384
    int m = tid >> 14;
    int e = tid & 16383;
    int n = e >> 7, k = e & 127;
    const float* src;
    int l = m & 3;
    switch (m >> 2) {
        case 0:  src = mW1 + l * 129 * 128; break;
        case 1:  src = mW2 + l * 128 * 128; break;
        case 2:  src = uW1 + l * 129 * 128; break;
        default: src = uW2 + l * 128 * 128; break;
    }
    float w = src[k * 128 + n];
    short hi = f2b(w);
    wh[tid] = hi;
    wl_[tid] = f2b(w - b2f(hi));
}

// ---------------- fused init + layer-0 W1 split-MFMA GEMM + counter zero ----------------
__global__ __launch_bounds__(256) void init_kernel(
    const float* __restrict__ xin, const int* __restrict__ z,
    const float* __restrict__ emb,
    const short* __restrict__ W1h, const short* __restrict__ W1l,
    float* __restrict__ x, float* __restrict__ traj,
    float* __restrict__ h, float* __restrict__ hW, int* __restrict__ cnt)
{
    __shared__ short sAH[16 * 136];   // h bf16 hi [m][k]
    __shared__ short sAL[16 * 136];   // h bf16 lo
    const int t = threadIdx.x;
    const int atom0 = blockIdx.x * 16;
    if (blockIdx.x == 0 && t < 64) cnt[t] = 0;
    if (t < 48) {
        int gi = atom0 * 3 + t;
        float v = xin[gi];
        x[gi] = v - floorf(v);
        traj[gi] = 0.f;
    }
    {
        const int r = t >> 4;
        const int f0 = (t & 15) * 8;
        const int a = atom0 + r;
        const float4* src = (const float4*)(emb + z[a] * FD + f0);
        float4 v0 = src[0], v1 = src[1];
        float4* dst = (float4*)(h + a * FD + f0);
        dst[0] = v0; dst[1] = v1;
        float vv[8] = {v0.x, v0.y, v0.z, v0.w, v1.x, v1.y, v1.z, v1.w};
        short8 shv, slv;
#pragma unroll
        for (int i = 0; i < 8; ++i) {
            short hi = f2b(vv[i]);
            shv[i] = hi; slv[i] = f2b(vv[i] - b2f(hi));
        }
        *(short8*)&sAH[r * 136 + f0] = shv;
        *(short8*)&sAL[r * 136 + f0] = slv;
    }
    __syncthreads();
    const int w = t >> 6, lane = t & 63, quad = lane >> 4, col = lane & 15;
    const int n0 = w * 32;
    f32x4 acc0 = {0.f, 0.f, 0.f, 0.f}, acc1 = {0.f, 0.f, 0.f, 0.f};
#pragma unroll
    for (int ks = 0; ks < 4; ++ks) {
        short8 ah = *(const short8*)&sAH[col * 136 + ks * 32 + quad * 8];
        short8 al = *(const short8*)&sAL[col * 136 + ks * 32 + quad * 8];
        short8 bh0 = ldb(W1h, n0 + col, ks, quad);
        short8 bl0 = ldb(W1l, n0 + col, ks, quad);
        short8 bh1 = ldb(W1h, n0 + 16 + col, ks, quad);
        short8 bl1 = ldb(W1l, n0 + 16 + col, ks, quad);
        acc0 = __builtin_amdgcn_mfma_f32_16x16x32_bf16(ah, bh0, acc0, 0, 0, 0);
        acc0 = __builtin_amdgcn_mfma_f32_16x16x32_bf16(ah, bl0, acc0, 0, 0, 0);
        acc0 = __builtin_amdgcn_mfma_f32_16x16x32_bf16(al, bh0, acc0, 0, 0, 0);
        acc1 = __builtin_amdgcn_mfma_f32_16x16x32_bf16(ah, bh1, acc1, 0, 0, 0);
        acc1 = __builtin_amdgcn_mfma_f32_16x16x32_bf16(ah, bl1, acc1, 0, 0, 0);
        acc1 = __builtin_amdgcn_mfma_f32_16x16x32_bf16(al, bh1, acc1, 0, 0, 0);
    }
#pragma unroll
    for (int nt = 0; nt < 2; ++nt) {
        int gn = n0 + nt * 16 + col;
        f32x4 av = (nt == 0) ? acc0 : acc1;
#pragma unroll
        for (int r = 0; r < 4; ++r)
            hW[(atom0 + quad * 4 + r) * FD + gn] = av[r];
    }
}

// ---------------- fused layer (split-MFMA): [knn] + dist + agg + W2 GEMM + residual (+pq) + next W1 ----------------
// grid 512 x 256; block = 8 atoms. mode_knn: compute knn in-block and emit idx/u0/dist0.
__global__ __launch_bounds__(256, 2) void layer_kernel(
    const float* __restrict__ hW, int* __restrict__ idxb,
    float* __restrict__ dist0, float* __restrict__ u0w,
    const float* __restrict__ x, const float* __restrict__ geo,
    int mode_knn, int use_d0, int use_geo,
    const float* __restrict__ wl, const float* __restrict__ b1,
    const short* __restrict__ W2h, const short* __restrict__ W2l,
    const float* __restrict__ b2,
    const short* __restrict__ W1nh, const short* __restrict__ W1nl,
    float* __restrict__ hWout,
    float* __restrict__ h, int write_h,
    const float* __restrict__ we_a, const float* __restrict__ we_p,
    float* __restrict__ p, float* __restrict__ q)
{
    __shared__ short sAggH[16 * 136]; // agg bf16 hi [m][k] (rows 8-15 unused)
    __shared__ short sAggL[16 * 136]; // agg bf16 lo
    __shared__ short sHnH[16 * 136];  // h_new bf16 hi
    __shared__ short sHnL[16 * 136];  // h_new bf16 lo
    __shared__ float sHf[8 * 136];    // h_new fp32 (for p,q)
    __shared__ int   sIdx[8 * KNN];
    __shared__ float sDist[8 * KNN];
    const int t = threadIdx.x;
    const int atom0 = blockIdx.x * 8;
    const int w = t >> 6, lane = t & 63, quad = lane >> 4, col = lane & 15;
    const int n0 = w * 32;
    // phase 1: indices + distances
    if (mode_knn) {
        // knn for own 8 atoms: 4 waves x 2 atoms (identity cell)
        for (int rep = 0; rep < 2; ++rep) {
            const int slot = w * 2 + rep;
            const int a = atom0 + slot;
            const int bS = a >> 8;
            const float xi0 = x[a * 3 + 0], xi1 = x[a * 3 + 1], xi2 = x[a * 3 + 2];
            unsigned long long key[4];
#pragma unroll
            for (int tt = 0; tt < 4; ++tt) {
                int jg = bS * NATS + lane + tt * 64;
                float d0 = x[jg * 3 + 0] - xi0; d0 -= rintf(d0);
                float d1 = x[jg * 3 + 1] - xi1; d1 -= rintf(d1);
                float d2 = x[jg * 3 + 2] - xi2; d2 -= rintf(d2);
                float dd = sqrtf(d0 * d0 + d1 * d1 + d2 * d2);
                if (jg == a) dd += 1e6f;        // exclude self (ref adds 1e6*eye)
                key[tt] = ((unsigned long long)__float_as_uint(dd) << 32) | (unsigned)jg;
            }
            int myj = 0;
            for (int sel = 0; sel < KNN; ++sel) {
                unsigned long long m = key[0];
                if (key[1] < m) m = key[1];
                if (key[2] < m) m = key[2];
                if (key[3] < m) m = key[3];
#pragma unroll
                for (int off = 32; off > 0; off >>= 1) {
                    unsigned lo = (unsigned)__shfl_xor((int)(unsigned)(m & 0xffffffffu), off);
                    unsigned hi = (unsigned)__shfl_xor((int)(unsigned)(m >> 32), off);
                    unsigned long long o = ((unsigned long long)hi << 32) | lo;
                    if (o < m) m = o;
                }
                int jw = (int)(m & 0xffffffffu);
                if (lane == 0) idxb[a * KNN + sel] = jw;
                if (lane == sel) myj = jw;
#pragma unroll
                for (int tt = 0; tt < 4; ++tt) if (key[tt] == m) key[tt] = ~0ull;
            }
            if (lane < KNN) {
                float f0 = x[myj * 3 + 0] - xi0; f0 -= rintf(f0);
                float f1 = x[myj * 3 + 1] - xi1; f1 -= rintf(f1);
                float f2 = x[myj * 3 + 2] - xi2; f2 -= rintf(f2);
                float dd = sqrtf(f0 * f0 + f1 * f1 + f2 * f2);
                float inv = 1.f / (dd + 1e-12f);
                int e = a * KNN + lane;
                u0w[e * 3 + 0] = f0 * inv; u0w[e * 3 + 1] = f1 * inv; u0w[e * 3 + 2] = f2 * inv;
                dist0[e] = dd;
                sIdx[slot * KNN + lane] = myj;
                sDist[slot * KNN + lane] = dd;
            }
        }
    } else if (t < 8 * KNN) {
        int a = atom0 + (t / KNN);
        int j = idxb[atom0 * KNN + t];
        sIdx[t] = j;
        float d;
        if (use_d0) {
            d = dist0[atom0 * KNN + t];
        } else {
            float f0 = x[j * 3 + 0] - x[a * 3 + 0]; f0 -= rintf(f0);
            float f1 = x[j * 3 + 1] - x[a * 3 + 1]; f1 -= rintf(f1);
            float f2 = x[j * 3 + 2] - x[a * 3 + 2]; f2 -= rintf(f2);
            float v0 = f0, v1 = f1, v2 = f2;
            if (use_geo) {
                const float* c = geo + (a >> 8) * 9;
                v0 = f0 * c[0] + f1 * c[3] + f2 * c[6];
                v1 = f0 * c[1] + f1 * c[4] + f2 * c[7];
                v2 = f0 * c[2] + f1 * c[5] + f2 * c[8];
            }
            d = sqrtf(v0 * v0 + v1 * v1 + v2 * v2);
        }
        sDist[t] = d;
    }
    __syncthreads();
    // phase 2: agg s_a[g] = sum_k silu(hW[j][g] + d*wl[g] + b1[g]) -> bf16 hi/lo
    {
        const int g = t & 127;
        const int sub = t >> 7;
        const float wlg = wl[g];
        const float b1g = b1[g];
#pragma unroll
        for (int rep = 0; rep < 4; ++rep) {
            const int a = rep * 2 + sub;
            float s = 0.f;
#pragma unroll 8
            for (int k = 0; k < KNN; ++k) {
                int j = sIdx[a * KNN + k];
                float v = hW[j * FD + g] + sDist[a * KNN + k] * wlg + b1g;
                s += silu_f(v);
            }
            short hi = f2b(s);
            sAggH[a * 136 + g] = hi;
            sAggL[a * 136 + g] = f2b(s - b2f(hi));
        }
    }
    __syncthreads();
    // phase 3: W2 split-MFMA GEMM (b-frags straight from global)
    f32x4 acc0 = {0.f, 0.f, 0.f, 0.f}, acc1 = {0.f, 0.f, 0.f, 0.f};
#pragma unroll
    for (int ks = 0; ks < 4; ++ks) {
        short8 ah = *(const short8*)&sAggH[col * 136 + ks * 32 + quad * 8];
        short8 al = *(const short8*)&sAggL[col * 136 + ks * 32 + quad * 8];
        short8 bh0 = ldb(W2h, n0 + col, ks, quad);
        short8 bl0 = ldb(W2l, n0 + col, ks, quad);
        short8 bh1 = ldb(W2h, n0 + 16 + col, ks, quad);
        short8 bl1 = ldb(W2l, n0 + 16 + col, ks, quad);
        acc0 = __builtin_amdgcn_mfma_f32_16x16x32_bf16(ah, bh0, acc0, 0, 0, 0);
        acc0 = __builtin_amdgcn_mfma_f32_16x16x32_bf16(ah, bl0, acc0, 0, 0, 0);
        acc0 = __builtin_amdgcn_mfma_f32_16x16x32_bf16(al, bh0, acc0, 0, 0, 0);
        acc1 = __builtin_amdgcn_mfma_f32_16x16x32_bf16(ah, bh1, acc1, 0, 0, 0);
        acc1 = __builtin_amdgcn_mfma_f32_16x16x32_bf16(ah, bl1, acc1, 0, 0, 0);
        acc1 = __builtin_amdgcn_mfma_f32_16x16x32_bf16(al, bh1, acc1, 0, 0, 0);
    }
    // epilogue: residual + silu; write h (optional); sHn hi/lo + sHf fp32
#pragma unroll
    for (int nt = 0; nt < 2; ++nt) {
        int gn = n0 + nt * 16 + col;
        float bb = b2[gn];
        f32x4 av = (nt == 0) ? acc0 : acc1;
#pragma unroll
        for (int r = 0; r < 4; ++r) {
            int row = quad * 4 + r;
            if (row < 8) {
                float o = h[(atom0 + row) * FD + gn] + silu_f(av[r] + bb);
                if (write_h) h[(atom0 + row) * FD + gn] = o;
                short hi = f2b(o);
                sHnH[row * 136 + gn] = hi;
                sHnL[row * 136 + gn] = f2b(o - b2f(hi));
                sHf[row * 136 + gn] = o;
            }
        }
    }
    __syncthreads();
    // phase 4: p,q epilogue (action layers) from fp32 h_new
    if (we_a != nullptr && t < 128) {
        int a = t >> 4, gr = t & 15;
        float pp = 0.f, qq = 0.f;
#pragma unroll
        for (int i = 0; i < 8; ++i) {
            int g = gr + i * 16;
            float hv = sHf[a * 136 + g];
            pp += hv * we_a[g];
            qq += hv * we_p[g];
        }
#pragma unroll
        for (int off = 8; off >= 1; off >>= 1) {
            pp += __shfl_xor(pp, off);
            qq += __shfl_xor(qq, off);
        }
        if (gr == 0) { p[atom0 + a] = pp; q[atom0 + a] = qq; }
    }
    // phase 5: next-layer W1 split-MFMA GEMM on h_new
    if (W1nh != nullptr) {
        f32x4 d0 = {0.f, 0.f, 0.f, 0.f}, d1 = {0.f, 0.f, 0.f, 0.f};
#pragma unroll
        for (int ks = 0; ks < 4; ++ks) {
            short8 ah = *(const short8*)&sHnH[col * 136 + ks * 32 + quad * 8];
            short8 al = *(const short8*)&sHnL[col * 136 + ks * 32 + quad * 8];
            short8 bh0 = ldb(W1nh, n0 + col, ks, quad);
            short8 bl0 = ldb(W1nl, n0 + col, ks, quad);
            short8 bh1 = ldb(W1nh, n0 + 16 + col, ks, quad);
            short8 bl1 = ldb(W1nl, n0 + 16 + col, ks, quad);
            d0 = __builtin_amdgcn_mfma_f32_16x16x32_bf16(ah, bh0, d0, 0, 0, 0);
            d0 = __builtin_amdgcn_mfma_f32_16x16x32_bf16(ah, bl0, d0, 0, 0, 0);
            d0 = __builtin_amdgcn_mfma_f32_16x16x32_bf16(al, bh0, d0, 0, 0, 0);
            d1 = __builtin_amdgcn_mfma_f32_16x16x32_bf16(ah, bh1, d1, 0, 0, 0);
            d1 = __builtin_amdgcn_mfma_f32_16x16x32_bf16(ah, bl1, d1, 0, 0, 0);
            d1 = __builtin_amdgcn_mfma_f32_16x16x32_bf16(al, bh1, d1, 0, 0, 0);
        }
#pragma unroll
        for (int nt = 0; nt < 2; ++nt) {
            int gn = n0 + nt * 16 + col;
            f32x4 av = (nt == 0) ? d0 : d1;
#pragma unroll
            for (int r = 0; r < 4; ++r) {
                int row = quad * 4 + r;
                if (row < 8)
                    hWout[(atom0 + row) * FD + gn] = av[r];
            }
        }
    }
}

// ---------------- fused accum + (last-block) rho/pos ----------------
// grid 1024 x 256; wave w handles atom blk*4+w. Per structure: 64 blocks; the last
// one (device-scope counter) reduces partials, runs the 3x3 chain, updates x/traj/out.
__global__ __launch_bounds__(256) void accum_kernel(
    const float* __restrict__ p, const float* __restrict__ q,
    const int* __restrict__ idxb, float* __restrict__ x,
    float* __restrict__ geo, int use_geo,
    const float* __restrict__ u0b,
    float* __restrict__ part, float* __restrict__ xcart,
    float* __restrict__ rho, float* __restrict__ traj,
    float* __restrict__ out, int* __restrict__ cnt, int first, int last)
{
    const int blk = blockIdx.x;
    const int t = threadIdx.x;
    const int w = t >> 6;
    const int lane = t & 63;
    const int a = blk * 4 + w;
    const int b = a >> 8;
    const int s = blk >> 6;             // structure of this block
    __shared__ float swe[4][KNN], swp[4][KNN];
    __shared__ float su[4][KNN][3], su0[4][KNN][3], sv[4][KNN][3];
    __shared__ float spart[4][18];
    __shared__ int   sLast;
    __shared__ float sIV[9];
    if (lane < KNN) {
        int e = a * KNN + lane;
        int j = idxb[e];
        swe[w][lane] = tanhf(p[a] + p[j]);
        swp[w][lane] = tanhf(q[a] + q[j]);
        float f0 = x[j * 3 + 0] - x[a * 3 + 0]; f0 -= rintf(f0);
        float f1 = x[j * 3 + 1] - x[a * 3 + 1]; f1 -= rintf(f1);
        float f2 = x[j * 3 + 2] - x[a * 3 + 2]; f2 -= rintf(f2);
        float v0 = f0, v1 = f1, v2 = f2;
        if (use_geo) {
            const float* c = geo + b * 9;
            v0 = f0 * c[0] + f1 * c[3] + f2 * c[6];
            v1 = f0 * c[1] + f1 * c[4] + f2 * c[7];
            v2 = f0 * c[2] + f1 * c[5] + f2 * c[8];
        }
        float dd = sqrtf(v0 * v0 + v1 * v1 + v2 * v2);
        float inv = 1.f / (dd + 1e-12f);
        sv[w][lane][0] = v0; sv[w][lane][1] = v1; sv[w][lane][2] = v2;
        su[w][lane][0] = v0 * inv; su[w][lane][1] = v1 * inv; su[w][lane][2] = v2 * inv;
        su0[w][lane][0] = u0b[e * 3]; su0[w][lane][1] = u0b[e * 3 + 1]; su0[w][lane][2] = u0b[e * 3 + 2];
    }
    __syncthreads();
    float r[21];
#pragma unroll
    for (int i = 0; i < 21; ++i) r[i] = 0.f;
    if (lane < KNN) {
        float wgt = swe[w][lane];
        float ux = su[w][lane][0], uy = su[w][lane][1], uz = su[w][lane][2];
        r[0] = wgt * ux * ux; r[1] = wgt * ux * uy; r[2] = wgt * ux * uz;
        r[3] = wgt * uy * ux; r[4] = wgt * uy * uy; r[5] = wgt * uy * uz;
        r[6] = wgt * uz * ux; r[7] = wgt * uz * uy; r[8] = wgt * uz * uz;
        float wp = swp[w][lane];
        r[18] = wp * sv[w][lane][0]; r[19] = wp * sv[w][lane][1]; r[20] = wp * sv[w][lane][2];
    }
#pragma unroll
    for (int tt = 0; tt < 9; ++tt) {
        int pr = lane + (tt << 6);          // 0..575 = 24*24
        int j = pr / KNN, k = pr - j * KNN;
        float c0x = su0[w][j][1] * su0[w][k][2] - su0[w][j][2] * su0[w][k][1];
        float c0y = su0[w][j][2] * su0[w][k][0] - su0[w][j][0] * su0[w][k][2];
        float c0z = su0[w][j][0] * su0[w][k][1] - su0[w][j][1] * su0[w][k][0];
        float nn2 = c0x * c0x + c0y * c0y + c0z * c0z;
        if (nn2 > 1e-6f) {
            float cx = su[w][j][1] * su[w][k][2] - su[w][j][2] * su[w][k][1];
            float cy = su[w][j][2] * su[w][k][0] - su[w][j][0] * su[w][k][2];
            float cz = su[w][j][0] * su[w][k][1] - su[w][j][1] * su[w][k][0];
            float wt = swe[w][j] * swe[w][k];
            r[9]  += wt * cx * cx; r[10] += wt * cx * cy; r[11] += wt * cx * cz;
            r[12] += wt * cy * cx; r[13] += wt * cy * cy; r[14] += wt * cy * cz;
            r[15] += wt * cz * cx; r[16] += wt * cz * cy; r[17] += wt * cz * cz;
        }
    }
#pragma unroll
    for (int off = 32; off > 0; off >>= 1)
#pragma unroll
        for (int i = 0; i < 21; ++i) r[i] += __shfl_down(r[i], off);
    if (lane == 0) {
#pragma unroll
        for (int i = 0; i < 18; ++i) spart[w][i] = r[i];
        xcart[a * 3 + 0] = EPSA * r[18];
        xcart[a * 3 + 1] = EPSA * r[19];
        xcart[a * 3 + 2] = EPSA * r[20];
    }
    __syncthreads();
    if (t < 18)
        part[blk * 18 + t] = spart[0][t] + spart[1][t] + spart[2][t] + spart[3][t];
    // ---- last-block-per-structure: reduce partials, 3x3 chain, pos/traj update ----
    __threadfence();                     // every thread: make its part/xcart stores device-visible
    __syncthreads();
    if (t == 0) {
        int old = atomicAdd(&cnt[s], 1); // device-scope
        sLast = (old == 63) ? 1 : 0;
    }
    __syncthreads();
    if (!sLast) return;
    __threadfence();                     // acquire: see all 64 blocks' part/xcart
    if (t < 64) {
        float rr[18];
#pragma unroll
        for (int i = 0; i < 18; ++i) rr[i] = part[(s * 64 + t) * 18 + i];
#pragma unroll
        for (int off = 32; off > 0; off >>= 1)
#pragma unroll
            for (int i = 0; i < 18; ++i) rr[i] += __shfl_down(rr[i], off);
        if (t == 0) {
            float A[9];
#pragma unroll
            for (int i = 0; i < 9; ++i) {
                float strain = rr[i] / 6144.f;          // NAT*K
                float tri = rr[9 + i] / 147456.f;       // NAT*K*K
                A[i] = ((i == 0 || i == 4 || i == 8) ? 1.f : 0.f) + EPSA * (strain + tri);
            }
            float N[9], IV[9];
            if (first) {
#pragma unroll
                for (int i = 0; i < 9; ++i) { N[i] = A[i]; IV[i] = (i == 0 || i == 4 || i == 8) ? 1.f : 0.f; }
            } else {
                float R[9], G[9];
#pragma unroll
                for (int i = 0; i < 9; ++i) { R[i] = rho[s * 9 + i]; G[i] = geo[s * 9 + i]; }
#pragma unroll
                for (int i = 0; i < 3; ++i)
#pragma unroll
                    for (int k = 0; k < 3; ++k)
                        N[i * 3 + k] = A[i * 3] * R[k] + A[i * 3 + 1] * R[3 + k] + A[i * 3 + 2] * R[6 + k];
                float det = G[0] * (G[4] * G[8] - G[5] * G[7])
                          - G[1] * (G[3] * G[8] - G[5] * G[6])
                          + G[2] * (G[3] * G[7] - G[4] * G[6]);
                float id = 1.f / det;
                IV[0] = (G[4] * G[8] - G[5] * G[7]) * id;
                IV[1] = (G[2] * G[7] - G[1] * G[8]) * id;
                IV[2] = (G[1] * G[5] - G[2] * G[4]) * id;
                IV[3] = (G[5] * G[6] - G[3] * G[8]) * id;
                IV[4] = (G[0] * G[8] - G[2] * G[6]) * id;
                IV[5] = (G[2] * G[3] - G[0] * G[5]) * id;
                IV[6] = (G[3] * G[7] - G[4] * G[6]) * id;
                IV[7] = (G[1] * G[6] - G[0] * G[7]) * id;
                IV[8] = (G[0] * G[4] - G[1] * G[3]) * id;
            }
#pragma unroll
            for (int i = 0; i < 9; ++i) {
                sIV[i] = IV[i];
                rho[s * 9 + i] = N[i];
                if (!last) geo[s * 9 + i] = N[i];
                else out[NATOMS * 3 + s * 9 + i] = N[i];
            }
        }
    }
    __syncthreads();
    for (int d = t; d < NATS * 3; d += 256) {
        int al = d / 3, dim = d - al * 3;
        int ga = s * NATS + al;
        int gi = ga * 3 + dim;
        float c0 = xcart[ga * 3 + 0], c1 = xcart[ga * 3 + 1], c2 = xcart[ga * 3 + 2];
        float tj = traj[gi] + xcart[gi];
        if (!last) {
            float xf = c0 * sIV[0 + dim] + c1 * sIV[3 + dim] + c2 * sIV[6 + dim];
            x[gi] += xf;
            traj[gi] = tj;
        } else {
            out[gi] = tj;
        }
    }
}

extern "C" void kernel_launch(void* const* d_in, const int* in_sizes, int n_in,
                              void* d_out, int out_size, void* d_ws, size_t ws_size,
                              hipStream_t stream)
{
    (void)in_sizes; (void)n_in; (void)out_size; (void)ws_size;
    const float* in_x = (const float*)d_in[1];
    const int*   z    = (const int*)d_in[2];
    const float* emb  = (const float*)d_in[4];
    const float* mW1  = (const float*)d_in[5];
    const float* mb1  = (const float*)d_in[6];
    const float* mW2  = (const float*)d_in[7];
    const float* mb2  = (const float*)d_in[8];
    const float* uW1  = (const float*)d_in[9];
    const float* ub1  = (const float*)d_in[10];
    const float* uW2  = (const float*)d_in[11];
    const float* ub2  = (const float*)d_in[12];
    const float* awe  = (const float*)d_in[13];
    const float* pwe  = (const float*)d_in[14];
    float* out = (float*)d_out;

    // workspace carve
    char* wsb = (char*)d_ws;
    size_t off = 0;
    auto carve = [&](size_t elems) {
        void* ptr = wsb + off;
        off += (elems * 4 + 255) & ~(size_t)255;
        return ptr;
    };
    float* traj  = (float*)carve(NATOMS * 3);
    float* part  = (float*)carve(1024 * 18);
    float* x     = (float*)carve(NATOMS * 3);
    float* xcart = (float*)carve(NATOMS * 3);
    float* p     = (float*)carve(NATOMS);
    float* q     = (float*)carve(NATOMS);
    float* rho   = (float*)carve(NB * 9);
    float* geo   = (float*)carve(NB * 9);
    float* u0    = (float*)carve(NEDGE * 3);
    float* dist0 = (float*)carve(NEDGE);
    float* h     = (float*)carve(NATOMS * FD);
    float* hWa   = (float*)carve(NATOMS * FD);
    float* hWb   = (float*)carve(NATOMS * FD);
    int*   idx   = (int*)carve(NEDGE);
    short* wth   = (short*)carve(16 * 16384 / 2);   // 16 bf16 hi matrices [n][k]
    short* wtl   = (short*)carve(16 * 16384 / 2);   // 16 bf16 lo matrices [n][k]
    int*   cnt   = (int*)carve(64);                 // 4 layers x 16 structures

    auto WH = [&](int m) { return wth + m * 16384; };
    auto WL = [&](int m) { return wtl + m * 16384; };
    // m: 0-3 mpnn W1, 4-7 mpnn W2, 8-11 upd W1, 12-15 upd W2

    prep_kernel<<<1024, 256, 0, stream>>>(mW1, mW2, uW1, uW2, wth, wtl);
    init_kernel<<<256, 256, 0, stream>>>(in_x, z, emb, WH(0), WL(0), x, traj, h, hWa, cnt);

    float* hw_in = hWa;
    float* hw_out = hWb;

    // message-passing layers (identity geometry; layer 0 computes knn in-block)
    for (int l = 0; l < 4; ++l) {
        int w1n = (l < 3) ? (l + 1) : 8;
        layer_kernel<<<512, 256, 0, stream>>>(hw_in, idx, dist0, u0, x, geo,
            (l == 0) ? 1 : 0, (l == 0) ? 0 : 1, 0,
            mW1 + l * 129 * 128 + 128 * 128, mb1 + l * 128,
            WH(4 + l), WL(4 + l), mb2 + l * 128,
            WH(w1n), WL(w1n), hw_out, h, 1,
            nullptr, nullptr, nullptr, nullptr);
        float* tmp = hw_in; hw_in = hw_out; hw_out = tmp;
    }
    // action layers
    for (int l = 0; l < 4; ++l) {
        const short* W1nh = (l < 3) ? WH(9 + l) : nullptr;
        const short* W1nl = (l < 3) ? WL(9 + l) : nullptr;
        layer_kernel<<<512, 256, 0, stream>>>(hw_in, idx, dist0, u0, x, geo,
            0, (l == 0) ? 1 : 0, (l > 0) ? 1 : 0,
            uW1 + l * 129 * 128 + 128 * 128, ub1 + l * 128,
            WH(12 + l), WL(12 + l), ub2 + l * 128,
            W1nh, W1nl, hw_out, h, (l < 3) ? 1 : 0,
            awe + l * 128, pwe + l * 128, p, q);
        float* tmp = hw_in; hw_in = hw_out; hw_out = tmp;
        accum_kernel<<<1024, 256, 0, stream>>>(p, q, idx, x, geo, (l > 0) ? 1 : 0,
            u0, part, xcart, rho, traj, out, cnt + l * 16,
            (l == 0) ? 1 : 0, (l == 3) ? 1 : 0);
    }
}

// Round 9
// 347.370 us; speedup vs baseline: 1.7110x; 1.7110x over previous
//
#include <hip/hip_runtime.h>

// Problem constants (reference: B=16, NAT=256, K=24, F=128, L=4, EPS=0.01)
#define NB 16
#define NATS 256
#define KNN 24
#define FD 128
#define EPSA 0.01f
#define NATOMS (NB * NATS)      // 4096
#define NEDGE (NATOMS * KNN)    // 98304

typedef __attribute__((ext_vector_type(8))) short short8;   // 8 bf16 (a/b frag)
typedef __attribute__((ext_vector_type(4))) float f32x4;    // C/D frag

__device__ __forceinline__ float silu_f(float v) { return v / (1.f + __expf(-v)); }

__device__ __forceinline__ short f2b(float f) {             // fp32 -> bf16 (RNE)
    union { float f; unsigned u; } v; v.f = f;
    unsigned r = v.u + 0x7FFFu + ((v.u >> 16) & 1u);
    return (short)(r >> 16);
}
__device__ __forceinline__ float b2f(short s) {
    return __uint_as_float(((unsigned)(unsigned short)s) << 16);
}
// b-frag: 16B contiguous chunk of transposed weight [n][k]
__device__ __forceinline__ short8 ldb(const short* __restrict__ W, int n, int ks, int quad) {
    return *(const short8*)&W[n * 128 + ks * 32 + quad * 8];
}

// ---------------- prep: transpose + bf16 hi/lo split of all 16 weight matrices ----------------
__global__ __launch_bounds__(256) void prep_kernel(
    const float* __restrict__ mW1, const float* __restrict__ mW2,
    const float* __restrict__ uW1, const float* __restrict__ uW2,
    short* __restrict__ wh, short* __restrict__ wl_)
{
    int tid = blockIdx.x * 256 + threadIdx.x;   // 1024*256 = 262144 = 16*16384
    int m = tid >> 14;
    int e = tid & 16383;
    int n = e >> 7, k = e & 127;
    const float* src;
    int l = m & 3;
    switch (m >> 2) {
        case 0:  src = mW1 + l * 129 * 128; break;
        case 1:  src = mW2 + l * 128 * 128; break;
        case 2:  src = uW1 + l * 129 * 128; break;
        default: src = uW2 + l * 128 * 128; break;
    }
    float w = src[k * 128 + n];
    short hi = f2b(w);
    wh[tid] = hi;
    wl_[tid] = f2b(w - b2f(hi));
}

// ---------------- fused init + layer-0 W1 split-MFMA GEMM ----------------
__global__ __launch_bounds__(256) void init_kernel(
    const float* __restrict__ xin, const int* __restrict__ z,
    const float* __restrict__ emb,
    const short* __restrict__ W1h, const short* __restrict__ W1l,
    float* __restrict__ x, float* __restrict__ traj,
    float* __restrict__ h, float* __restrict__ hW)
{
    __shared__ short sAH[16 * 136];   // h bf16 hi [m][k]
    __shared__ short sAL[16 * 136];   // h bf16 lo
    const int t = threadIdx.x;
    const int atom0 = blockIdx.x * 16;
    if (t < 48) {
        int gi = atom0 * 3 + t;
        float v = xin[gi];
        x[gi] = v - floorf(v);
        traj[gi] = 0.f;
    }
    {
        const int r = t >> 4;
        const int f0 = (t & 15) * 8;
        const int a = atom0 + r;
        const float4* src = (const float4*)(emb + z[a] * FD + f0);
        float4 v0 = src[0], v1 = src[1];
        float4* dst = (float4*)(h + a * FD + f0);
        dst[0] = v0; dst[1] = v1;
        float vv[8] = {v0.x, v0.y, v0.z, v0.w, v1.x, v1.y, v1.z, v1.w};
        short8 shv, slv;
#pragma unroll
        for (int i = 0; i < 8; ++i) {
            short hi = f2b(vv[i]);
            shv[i] = hi; slv[i] = f2b(vv[i] - b2f(hi));
        }
        *(short8*)&sAH[r * 136 + f0] = shv;
        *(short8*)&sAL[r * 136 + f0] = slv;
    }
    __syncthreads();
    const int w = t >> 6, lane = t & 63, quad = lane >> 4, col = lane & 15;
    const int n0 = w * 32;
    f32x4 acc0 = {0.f, 0.f, 0.f, 0.f}, acc1 = {0.f, 0.f, 0.f, 0.f};
#pragma unroll
    for (int ks = 0; ks < 4; ++ks) {
        short8 ah = *(const short8*)&sAH[col * 136 + ks * 32 + quad * 8];
        short8 al = *(const short8*)&sAL[col * 136 + ks * 32 + quad * 8];
        short8 bh0 = ldb(W1h, n0 + col, ks, quad);
        short8 bl0 = ldb(W1l, n0 + col, ks, quad);
        short8 bh1 = ldb(W1h, n0 + 16 + col, ks, quad);
        short8 bl1 = ldb(W1l, n0 + 16 + col, ks, quad);
        acc0 = __builtin_amdgcn_mfma_f32_16x16x32_bf16(ah, bh0, acc0, 0, 0, 0);
        acc0 = __builtin_amdgcn_mfma_f32_16x16x32_bf16(ah, bl0, acc0, 0, 0, 0);
        acc0 = __builtin_amdgcn_mfma_f32_16x16x32_bf16(al, bh0, acc0, 0, 0, 0);
        acc1 = __builtin_amdgcn_mfma_f32_16x16x32_bf16(ah, bh1, acc1, 0, 0, 0);
        acc1 = __builtin_amdgcn_mfma_f32_16x16x32_bf16(ah, bl1, acc1, 0, 0, 0);
        acc1 = __builtin_amdgcn_mfma_f32_16x16x32_bf16(al, bh1, acc1, 0, 0, 0);
    }
#pragma unroll
    for (int nt = 0; nt < 2; ++nt) {
        int gn = n0 + nt * 16 + col;
        f32x4 av = (nt == 0) ? acc0 : acc1;
#pragma unroll
        for (int r = 0; r < 4; ++r)
            hW[(atom0 + quad * 4 + r) * FD + gn] = av[r];
    }
}

// ---------------- fused layer (split-MFMA): [knn] + dist + agg + W2 GEMM + residual (+pq) + next W1 ----------------
// grid 512 x 256; block = 8 atoms. mode_knn: compute knn in-block and emit idx/u0/dist0.
__global__ __launch_bounds__(256, 2) void layer_kernel(
    const float* __restrict__ hW, int* __restrict__ idxb,
    float* __restrict__ dist0, float* __restrict__ u0w,
    const float* __restrict__ x, const float* __restrict__ geo,
    int mode_knn, int use_d0, int use_geo,
    const float* __restrict__ wl, const float* __restrict__ b1,
    const short* __restrict__ W2h, const short* __restrict__ W2l,
    const float* __restrict__ b2,
    const short* __restrict__ W1nh, const short* __restrict__ W1nl,
    float* __restrict__ hWout,
    float* __restrict__ h, int write_h,
    const float* __restrict__ we_a, const float* __restrict__ we_p,
    float* __restrict__ p, float* __restrict__ q)
{
    __shared__ short sAggH[16 * 136]; // agg bf16 hi [m][k] (rows 8-15 unused)
    __shared__ short sAggL[16 * 136]; // agg bf16 lo
    __shared__ short sHnH[16 * 136];  // h_new bf16 hi
    __shared__ short sHnL[16 * 136];  // h_new bf16 lo
    __shared__ float sHf[8 * 136];    // h_new fp32 (for p,q)
    __shared__ int   sIdx[8 * KNN];
    __shared__ float sDist[8 * KNN];
    const int t = threadIdx.x;
    const int atom0 = blockIdx.x * 8;
    const int w = t >> 6, lane = t & 63, quad = lane >> 4, col = lane & 15;
    const int n0 = w * 32;
    // phase 1: indices + distances
    if (mode_knn) {
        // knn for own 8 atoms: 4 waves x 2 atoms (identity cell)
        for (int rep = 0; rep < 2; ++rep) {
            const int slot = w * 2 + rep;
            const int a = atom0 + slot;
            const int bS = a >> 8;
            const float xi0 = x[a * 3 + 0], xi1 = x[a * 3 + 1], xi2 = x[a * 3 + 2];
            unsigned long long key[4];
#pragma unroll
            for (int tt = 0; tt < 4; ++tt) {
                int jg = bS * NATS + lane + tt * 64;
                float d0 = x[jg * 3 + 0] - xi0; d0 -= rintf(d0);
                float d1 = x[jg * 3 + 1] - xi1; d1 -= rintf(d1);
                float d2 = x[jg * 3 + 2] - xi2; d2 -= rintf(d2);
                float dd = sqrtf(d0 * d0 + d1 * d1 + d2 * d2);
                if (jg == a) dd += 1e6f;        // exclude self (ref adds 1e6*eye)
                key[tt] = ((unsigned long long)__float_as_uint(dd) << 32) | (unsigned)jg;
            }
            int myj = 0;
            for (int sel = 0; sel < KNN; ++sel) {
                unsigned long long m = key[0];
                if (key[1] < m) m = key[1];
                if (key[2] < m) m = key[2];
                if (key[3] < m) m = key[3];
#pragma unroll
                for (int off = 32; off > 0; off >>= 1) {
                    unsigned lo = (unsigned)__shfl_xor((int)(unsigned)(m & 0xffffffffu), off);
                    unsigned hi = (unsigned)__shfl_xor((int)(unsigned)(m >> 32), off);
                    unsigned long long o = ((unsigned long long)hi << 32) | lo;
                    if (o < m) m = o;
                }
                int jw = (int)(m & 0xffffffffu);
                if (lane == 0) idxb[a * KNN + sel] = jw;
                if (lane == sel) myj = jw;
#pragma unroll
                for (int tt = 0; tt < 4; ++tt) if (key[tt] == m) key[tt] = ~0ull;
            }
            if (lane < KNN) {
                float f0 = x[myj * 3 + 0] - xi0; f0 -= rintf(f0);
                float f1 = x[myj * 3 + 1] - xi1; f1 -= rintf(f1);
                float f2 = x[myj * 3 + 2] - xi2; f2 -= rintf(f2);
                float dd = sqrtf(f0 * f0 + f1 * f1 + f2 * f2);
                float inv = 1.f / (dd + 1e-12f);
                int e = a * KNN + lane;
                u0w[e * 3 + 0] = f0 * inv; u0w[e * 3 + 1] = f1 * inv; u0w[e * 3 + 2] = f2 * inv;
                dist0[e] = dd;
                sIdx[slot * KNN + lane] = myj;
                sDist[slot * KNN + lane] = dd;
            }
        }
    } else if (t < 8 * KNN) {
        int a = atom0 + (t / KNN);
        int j = idxb[atom0 * KNN + t];
        sIdx[t] = j;
        float d;
        if (use_d0) {
            d = dist0[atom0 * KNN + t];
        } else {
            float f0 = x[j * 3 + 0] - x[a * 3 + 0]; f0 -= rintf(f0);
            float f1 = x[j * 3 + 1] - x[a * 3 + 1]; f1 -= rintf(f1);
            float f2 = x[j * 3 + 2] - x[a * 3 + 2]; f2 -= rintf(f2);
            float v0 = f0, v1 = f1, v2 = f2;
            if (use_geo) {
                const float* c = geo + (a >> 8) * 9;
                v0 = f0 * c[0] + f1 * c[3] + f2 * c[6];
                v1 = f0 * c[1] + f1 * c[4] + f2 * c[7];
                v2 = f0 * c[2] + f1 * c[5] + f2 * c[8];
            }
            d = sqrtf(v0 * v0 + v1 * v1 + v2 * v2);
        }
        sDist[t] = d;
    }
    __syncthreads();
    // phase 2: agg s_a[g] = sum_k silu(hW[j][g] + d*wl[g] + b1[g]) -> bf16 hi/lo
    {
        const int g = t & 127;
        const int sub = t >> 7;
        const float wlg = wl[g];
        const float b1g = b1[g];
#pragma unroll
        for (int rep = 0; rep < 4; ++rep) {
            const int a = rep * 2 + sub;
            float s = 0.f;
#pragma unroll 8
            for (int k = 0; k < KNN; ++k) {
                int j = sIdx[a * KNN + k];
                float v = hW[j * FD + g] + sDist[a * KNN + k] * wlg + b1g;
                s += silu_f(v);
            }
            short hi = f2b(s);
            sAggH[a * 136 + g] = hi;
            sAggL[a * 136 + g] = f2b(s - b2f(hi));
        }
    }
    __syncthreads();
    // phase 3: W2 split-MFMA GEMM (b-frags straight from global)
    f32x4 acc0 = {0.f, 0.f, 0.f, 0.f}, acc1 = {0.f, 0.f, 0.f, 0.f};
#pragma unroll
    for (int ks = 0; ks < 4; ++ks) {
        short8 ah = *(const short8*)&sAggH[col * 136 + ks * 32 + quad * 8];
        short8 al = *(const short8*)&sAggL[col * 136 + ks * 32 + quad * 8];
        short8 bh0 = ldb(W2h, n0 + col, ks, quad);
        short8 bl0 = ldb(W2l, n0 + col, ks, quad);
        short8 bh1 = ldb(W2h, n0 + 16 + col, ks, quad);
        short8 bl1 = ldb(W2l, n0 + 16 + col, ks, quad);
        acc0 = __builtin_amdgcn_mfma_f32_16x16x32_bf16(ah, bh0, acc0, 0, 0, 0);
        acc0 = __builtin_amdgcn_mfma_f32_16x16x32_bf16(ah, bl0, acc0, 0, 0, 0);
        acc0 = __builtin_amdgcn_mfma_f32_16x16x32_bf16(al, bh0, acc0, 0, 0, 0);
        acc1 = __builtin_amdgcn_mfma_f32_16x16x32_bf16(ah, bh1, acc1, 0, 0, 0);
        acc1 = __builtin_amdgcn_mfma_f32_16x16x32_bf16(ah, bl1, acc1, 0, 0, 0);
        acc1 = __builtin_amdgcn_mfma_f32_16x16x32_bf16(al, bh1, acc1, 0, 0, 0);
    }
    // epilogue: residual + silu; write h (optional); sHn hi/lo + sHf fp32
#pragma unroll
    for (int nt = 0; nt < 2; ++nt) {
        int gn = n0 + nt * 16 + col;
        float bb = b2[gn];
        f32x4 av = (nt == 0) ? acc0 : acc1;
#pragma unroll
        for (int r = 0; r < 4; ++r) {
            int row = quad * 4 + r;
            if (row < 8) {
                float o = h[(atom0 + row) * FD + gn] + silu_f(av[r] + bb);
                if (write_h) h[(atom0 + row) * FD + gn] = o;
                short hi = f2b(o);
                sHnH[row * 136 + gn] = hi;
                sHnL[row * 136 + gn] = f2b(o - b2f(hi));
                sHf[row * 136 + gn] = o;
            }
        }
    }
    __syncthreads();
    // phase 4: p,q epilogue (action layers) from fp32 h_new
    if (we_a != nullptr && t < 128) {
        int a = t >> 4, gr = t & 15;
        float pp = 0.f, qq = 0.f;
#pragma unroll
        for (int i = 0; i < 8; ++i) {
            int g = gr + i * 16;
            float hv = sHf[a * 136 + g];
            pp += hv * we_a[g];
            qq += hv * we_p[g];
        }
#pragma unroll
        for (int off = 8; off >= 1; off >>= 1) {
            pp += __shfl_xor(pp, off);
            qq += __shfl_xor(qq, off);
        }
        if (gr == 0) { p[atom0 + a] = pp; q[atom0 + a] = qq; }
    }
    // phase 5: next-layer W1 split-MFMA GEMM on h_new
    if (W1nh != nullptr) {
        f32x4 d0 = {0.f, 0.f, 0.f, 0.f}, d1 = {0.f, 0.f, 0.f, 0.f};
#pragma unroll
        for (int ks = 0; ks < 4; ++ks) {
            short8 ah = *(const short8*)&sHnH[col * 136 + ks * 32 + quad * 8];
            short8 al = *(const short8*)&sHnL[col * 136 + ks * 32 + quad * 8];
            short8 bh0 = ldb(W1nh, n0 + col, ks, quad);
            short8 bl0 = ldb(W1nl, n0 + col, ks, quad);
            short8 bh1 = ldb(W1nh, n0 + 16 + col, ks, quad);
            short8 bl1 = ldb(W1nl, n0 + 16 + col, ks, quad);
            d0 = __builtin_amdgcn_mfma_f32_16x16x32_bf16(ah, bh0, d0, 0, 0, 0);
            d0 = __builtin_amdgcn_mfma_f32_16x16x32_bf16(ah, bl0, d0, 0, 0, 0);
            d0 = __builtin_amdgcn_mfma_f32_16x16x32_bf16(al, bh0, d0, 0, 0, 0);
            d1 = __builtin_amdgcn_mfma_f32_16x16x32_bf16(ah, bh1, d1, 0, 0, 0);
            d1 = __builtin_amdgcn_mfma_f32_16x16x32_bf16(ah, bl1, d1, 0, 0, 0);
            d1 = __builtin_amdgcn_mfma_f32_16x16x32_bf16(al, bh1, d1, 0, 0, 0);
        }
#pragma unroll
        for (int nt = 0; nt < 2; ++nt) {
            int gn = n0 + nt * 16 + col;
            f32x4 av = (nt == 0) ? d0 : d1;
#pragma unroll
            for (int r = 0; r < 4; ++r) {
                int row = quad * 4 + r;
                if (row < 8)
                    hWout[(atom0 + row) * FD + gn] = av[r];
            }
        }
    }
}

// ---------------- per-atom action accumulation (inline vec/u): partials + x_cart ----------------
__global__ __launch_bounds__(256) void accum_kernel(
    const float* __restrict__ p, const float* __restrict__ q,
    const int* __restrict__ idxb, const float* __restrict__ x,
    const float* __restrict__ geo, int use_geo,
    const float* __restrict__ u0b,
    float* __restrict__ part, float* __restrict__ xcart)
{
    const int blk = blockIdx.x;
    const int t = threadIdx.x;
    const int w = t >> 6;
    const int lane = t & 63;
    const int a = blk * 4 + w;
    const int b = a >> 8;
    __shared__ float swe[4][KNN], swp[4][KNN];
    __shared__ float su[4][KNN][3], su0[4][KNN][3], sv[4][KNN][3];
    __shared__ float spart[4][18];
    if (lane < KNN) {
        int e = a * KNN + lane;
        int j = idxb[e];
        swe[w][lane] = tanhf(p[a] + p[j]);
        swp[w][lane] = tanhf(q[a] + q[j]);
        float f0 = x[j * 3 + 0] - x[a * 3 + 0]; f0 -= rintf(f0);
        float f1 = x[j * 3 + 1] - x[a * 3 + 1]; f1 -= rintf(f1);
        float f2 = x[j * 3 + 2] - x[a * 3 + 2]; f2 -= rintf(f2);
        float v0 = f0, v1 = f1, v2 = f2;
        if (use_geo) {
            const float* c = geo + b * 9;
            v0 = f0 * c[0] + f1 * c[3] + f2 * c[6];
            v1 = f0 * c[1] + f1 * c[4] + f2 * c[7];
            v2 = f0 * c[2] + f1 * c[5] + f2 * c[8];
        }
        float dd = sqrtf(v0 * v0 + v1 * v1 + v2 * v2);
        float inv = 1.f / (dd + 1e-12f);
        sv[w][lane][0] = v0; sv[w][lane][1] = v1; sv[w][lane][2] = v2;
        su[w][lane][0] = v0 * inv; su[w][lane][1] = v1 * inv; su[w][lane][2] = v2 * inv;
        su0[w][lane][0] = u0b[e * 3]; su0[w][lane][1] = u0b[e * 3 + 1]; su0[w][lane][2] = u0b[e * 3 + 2];
    }
    __syncthreads();
    float r[21];
#pragma unroll
    for (int i = 0; i < 21; ++i) r[i] = 0.f;
    if (lane < KNN) {
        float wgt = swe[w][lane];
        float ux = su[w][lane][0], uy = su[w][lane][1], uz = su[w][lane][2];
        r[0] = wgt * ux * ux; r[1] = wgt * ux * uy; r[2] = wgt * ux * uz;
        r[3] = wgt * uy * ux; r[4] = wgt * uy * uy; r[5] = wgt * uy * uz;
        r[6] = wgt * uz * ux; r[7] = wgt * uz * uy; r[8] = wgt * uz * uz;
        float wp = swp[w][lane];
        r[18] = wp * sv[w][lane][0]; r[19] = wp * sv[w][lane][1]; r[20] = wp * sv[w][lane][2];
    }
#pragma unroll
    for (int tt = 0; tt < 9; ++tt) {
        int pr = lane + (tt << 6);          // 0..575 = 24*24
        int j = pr / KNN, k = pr - j * KNN;
        float c0x = su0[w][j][1] * su0[w][k][2] - su0[w][j][2] * su0[w][k][1];
        float c0y = su0[w][j][2] * su0[w][k][0] - su0[w][j][0] * su0[w][k][2];
        float c0z = su0[w][j][0] * su0[w][k][1] - su0[w][j][1] * su0[w][k][0];
        float nn2 = c0x * c0x + c0y * c0y + c0z * c0z;
        if (nn2 > 1e-6f) {
            float cx = su[w][j][1] * su[w][k][2] - su[w][j][2] * su[w][k][1];
            float cy = su[w][j][2] * su[w][k][0] - su[w][j][0] * su[w][k][2];
            float cz = su[w][j][0] * su[w][k][1] - su[w][j][1] * su[w][k][0];
            float wt = swe[w][j] * swe[w][k];
            r[9]  += wt * cx * cx; r[10] += wt * cx * cy; r[11] += wt * cx * cz;
            r[12] += wt * cy * cx; r[13] += wt * cy * cy; r[14] += wt * cy * cz;
            r[15] += wt * cz * cx; r[16] += wt * cz * cy; r[17] += wt * cz * cz;
        }
    }
#pragma unroll
    for (int off = 32; off > 0; off >>= 1)
#pragma unroll
        for (int i = 0; i < 21; ++i) r[i] += __shfl_down(r[i], off);
    if (lane == 0) {
#pragma unroll
        for (int i = 0; i < 18; ++i) spart[w][i] = r[i];
        xcart[a * 3 + 0] = EPSA * r[18];
        xcart[a * 3 + 1] = EPSA * r[19];
        xcart[a * 3 + 2] = EPSA * r[20];
    }
    __syncthreads();
    if (t < 18)
        part[blk * 18 + t] = spart[0][t] + spart[1][t] + spart[2][t] + spart[3][t];
}

// ---------------- fused rho + pos ----------------
__global__ __launch_bounds__(256) void rho_pos_kernel(const float* __restrict__ part,
    const float* __restrict__ xcart,
    float* __restrict__ rho, float* __restrict__ geo,
    float* __restrict__ x, float* __restrict__ traj,
    float* __restrict__ out, int first, int last)
{
    const int b = blockIdx.x;
    const int t = threadIdx.x;
    __shared__ float sIV[9];
    if (t < 64) {
        float r[18];
#pragma unroll
        for (int i = 0; i < 18; ++i) r[i] = part[(b * 64 + t) * 18 + i];
#pragma unroll
        for (int off = 32; off > 0; off >>= 1)
#pragma unroll
            for (int i = 0; i < 18; ++i) r[i] += __shfl_down(r[i], off);
        if (t == 0) {
            float A[9];
#pragma unroll
            for (int i = 0; i < 9; ++i) {
                float strain = r[i] / 6144.f;           // NAT*K
                float tri = r[9 + i] / 147456.f;        // NAT*K*K
                A[i] = ((i == 0 || i == 4 || i == 8) ? 1.f : 0.f) + EPSA * (strain + tri);
            }
            float N[9], IV[9];
            if (first) {
#pragma unroll
                for (int i = 0; i < 9; ++i) { N[i] = A[i]; IV[i] = (i == 0 || i == 4 || i == 8) ? 1.f : 0.f; }
            } else {
                float R[9], G[9];
#pragma unroll
                for (int i = 0; i < 9; ++i) { R[i] = rho[b * 9 + i]; G[i] = geo[b * 9 + i]; }
#pragma unroll
                for (int i = 0; i < 3; ++i)
#pragma unroll
                    for (int k = 0; k < 3; ++k)
                        N[i * 3 + k] = A[i * 3] * R[k] + A[i * 3 + 1] * R[3 + k] + A[i * 3 + 2] * R[6 + k];
                float det = G[0] * (G[4] * G[8] - G[5] * G[7])
                          - G[1] * (G[3] * G[8] - G[5] * G[6])
                          + G[2] * (G[3] * G[7] - G[4] * G[6]);
                float id = 1.f / det;
                IV[0] = (G[4] * G[8] - G[5] * G[7]) * id;
                IV[1] = (G[2] * G[7] - G[1] * G[8]) * id;
                IV[2] = (G[1] * G[5] - G[2] * G[4]) * id;
                IV[3] = (G[5] * G[6] - G[3] * G[8]) * id;
                IV[4] = (G[0] * G[8] - G[2] * G[6]) * id;
                IV[5] = (G[2] * G[3] - G[0] * G[5]) * id;
                IV[6] = (G[3] * G[7] - G[4] * G[6]) * id;
                IV[7] = (G[1] * G[6] - G[0] * G[7]) * id;
                IV[8] = (G[0] * G[4] - G[1] * G[3]) * id;
            }
#pragma unroll
            for (int i = 0; i < 9; ++i) {
                sIV[i] = IV[i];
                rho[b * 9 + i] = N[i];
                if (!last) geo[b * 9 + i] = N[i];
                else out[NATOMS * 3 + b * 9 + i] = N[i];
            }
        }
    }
    __syncthreads();
    for (int d = t; d < NATS * 3; d += 256) {
        int al = d / 3, dim = d - al * 3;
        int ga = b * NATS + al;
        int gi = ga * 3 + dim;
        float c0 = xcart[ga * 3 + 0], c1 = xcart[ga * 3 + 1], c2 = xcart[ga * 3 + 2];
        float tj = traj[gi] + xcart[gi];
        if (!last) {
            float xf = c0 * sIV[0 + dim] + c1 * sIV[3 + dim] + c2 * sIV[6 + dim];
            x[gi] += xf;
            traj[gi] = tj;
        } else {
            out[gi] = tj;
        }
    }
}

extern "C" void kernel_launch(void* const* d_in, const int* in_sizes, int n_in,
                              void* d_out, int out_size, void* d_ws, size_t ws_size,
                              hipStream_t stream)
{
    (void)in_sizes; (void)n_in; (void)out_size; (void)ws_size;
    const float* in_x = (const float*)d_in[1];
    const int*   z    = (const int*)d_in[2];
    const float* emb  = (const float*)d_in[4];
    const float* mW1  = (const float*)d_in[5];
    const float* mb1  = (const float*)d_in[6];
    const float* mW2  = (const float*)d_in[7];
    const float* mb2  = (const float*)d_in[8];
    const float* uW1  = (const float*)d_in[9];
    const float* ub1  = (const float*)d_in[10];
    const float* uW2  = (const float*)d_in[11];
    const float* ub2  = (const float*)d_in[12];
    const float* awe  = (const float*)d_in[13];
    const float* pwe  = (const float*)d_in[14];
    float* out = (float*)d_out;

    // workspace carve
    char* wsb = (char*)d_ws;
    size_t off = 0;
    auto carve = [&](size_t elems) {
        void* ptr = wsb + off;
        off += (elems * 4 + 255) & ~(size_t)255;
        return ptr;
    };
    float* traj  = (float*)carve(NATOMS * 3);
    float* part  = (float*)carve(1024 * 18);
    float* x     = (float*)carve(NATOMS * 3);
    float* xcart = (float*)carve(NATOMS * 3);
    float* p     = (float*)carve(NATOMS);
    float* q     = (float*)carve(NATOMS);
    float* rho   = (float*)carve(NB * 9);
    float* geo   = (float*)carve(NB * 9);
    float* u0    = (float*)carve(NEDGE * 3);
    float* dist0 = (float*)carve(NEDGE);
    float* h     = (float*)carve(NATOMS * FD);
    float* hWa   = (float*)carve(NATOMS * FD);
    float* hWb   = (float*)carve(NATOMS * FD);
    int*   idx   = (int*)carve(NEDGE);
    short* wth   = (short*)carve(16 * 16384 / 2);   // 16 bf16 hi matrices [n][k]
    short* wtl   = (short*)carve(16 * 16384 / 2);   // 16 bf16 lo matrices [n][k]

    auto WH = [&](int m) { return wth + m * 16384; };
    auto WL = [&](int m) { return wtl + m * 16384; };
    // m: 0-3 mpnn W1, 4-7 mpnn W2, 8-11 upd W1, 12-15 upd W2

    prep_kernel<<<1024, 256, 0, stream>>>(mW1, mW2, uW1, uW2, wth, wtl);
    init_kernel<<<256, 256, 0, stream>>>(in_x, z, emb, WH(0), WL(0), x, traj, h, hWa);

    float* hw_in = hWa;
    float* hw_out = hWb;

    // message-passing layers (identity geometry; layer 0 computes knn in-block)
    for (int l = 0; l < 4; ++l) {
        int w1n = (l < 3) ? (l + 1) : 8;
        layer_kernel<<<512, 256, 0, stream>>>(hw_in, idx, dist0, u0, x, geo,
            (l == 0) ? 1 : 0, (l == 0) ? 0 : 1, 0,
            mW1 + l * 129 * 128 + 128 * 128, mb1 + l * 128,
            WH(4 + l), WL(4 + l), mb2 + l * 128,
            WH(w1n), WL(w1n), hw_out, h, 1,
            nullptr, nullptr, nullptr, nullptr);
        float* tmp = hw_in; hw_in = hw_out; hw_out = tmp;
    }
    // action layers
    for (int l = 0; l < 4; ++l) {
        const short* W1nh = (l < 3) ? WH(9 + l) : nullptr;
        const short* W1nl = (l < 3) ? WL(9 + l) : nullptr;
        layer_kernel<<<512, 256, 0, stream>>>(hw_in, idx, dist0, u0, x, geo,
            0, (l == 0) ? 1 : 0, (l > 0) ? 1 : 0,
            uW1 + l * 129 * 128 + 128 * 128, ub1 + l * 128,
            WH(12 + l), WL(12 + l), ub2 + l * 128,
            W1nh, W1nl, hw_out, h, (l < 3) ? 1 : 0,
            awe + l * 128, pwe + l * 128, p, q);
        float* tmp = hw_in; hw_in = hw_out; hw_out = tmp;
        accum_kernel<<<1024, 256, 0, stream>>>(p, q, idx, x, geo, (l > 0) ? 1 : 0,
            u0, part, xcart);
        rho_pos_kernel<<<NB, 256, 0, stream>>>(part, xcart, rho, geo, x, traj, out,
            (l == 0) ? 1 : 0, (l == 3) ? 1 : 0);
    }
}

// Round 10
// 324.838 us; speedup vs baseline: 1.8296x; 1.0694x over previous
//
#include <hip/hip_runtime.h>

// Problem constants (reference: B=16, NAT=256, K=24, F=128, L=4, EPS=0.01)
#define NB 16
#define NATS 256
#define KNN 24
#define FD 128
#define EPSA 0.01f
#define NATOMS (NB * NATS)      // 4096
#define NEDGE (NATOMS * KNN)    // 98304

typedef __attribute__((ext_vector_type(8))) short short8;   // 8 bf16 (a/b frag)
typedef __attribute__((ext_vector_type(4))) float f32x4;    // C/D frag

// fast transcendentals: v_rcp_f32 instead of IEEE division sequence (no -ffast-math
// in harness compile). Limits are exact: exp->inf => rcp->0; exp->0 => rcp(1)=1.
__device__ __forceinline__ float fast_rcp(float x) { return __builtin_amdgcn_rcpf(x); }
__device__ __forceinline__ float silu_f(float v) { return v * fast_rcp(1.f + __expf(-v)); }
__device__ __forceinline__ float tanh_f(float x) { return 1.f - 2.f * fast_rcp(__expf(2.f * x) + 1.f); }

__device__ __forceinline__ short f2b(float f) {             // fp32 -> bf16 (RNE)
    union { float f; unsigned u; } v; v.f = f;
    unsigned r = v.u + 0x7FFFu + ((v.u >> 16) & 1u);
    return (short)(r >> 16);
}
__device__ __forceinline__ float b2f(short s) {
    return __uint_as_float(((unsigned)(unsigned short)s) << 16);
}
// b-frag: 16B contiguous chunk of transposed weight [n][k]
__device__ __forceinline__ short8 ldb(const short* __restrict__ W, int n, int ks, int quad) {
    return *(const short8*)&W[n * 128 + ks * 32 + quad * 8];
}

// ---------------- prep: transpose + bf16 hi/lo split of all 16 weight matrices ----------------
__global__ __launch_bounds__(256) void prep_kernel(
    const float* __restrict__ mW1, const float* __restrict__ mW2,
    const float* __restrict__ uW1, const float* __restrict__ uW2,
    short* __restrict__ wh, short* __restrict__ wl_)
{
    int tid = blockIdx.x * 256 + threadIdx.x;   // 1024*256 = 262144 = 16*16384
    int m = tid >> 14;
    int e = tid & 16383;
    int n = e >> 7, k = e & 127;
    const float* src;
    int l = m & 3;
    switch (m >> 2) {
        case 0:  src = mW1 + l * 129 * 128; break;
        case 1:  src = mW2 + l * 128 * 128; break;
        case 2:  src = uW1 + l * 129 * 128; break;
        default: src = uW2 + l * 128 * 128; break;
    }
    float w = src[k * 128 + n];
    short hi = f2b(w);
    wh[tid] = hi;
    wl_[tid] = f2b(w - b2f(hi));
}

// ---------------- fused init + layer-0 W1 split-MFMA GEMM ----------------
__global__ __launch_bounds__(256) void init_kernel(
    const float* __restrict__ xin, const int* __restrict__ z,
    const float* __restrict__ emb,
    const short* __restrict__ W1h, const short* __restrict__ W1l,
    float* __restrict__ x, float* __restrict__ traj,
    float* __restrict__ h, float* __restrict__ hW)
{
    __shared__ short sAH[16 * 136];   // h bf16 hi [m][k]
    __shared__ short sAL[16 * 136];   // h bf16 lo
    const int t = threadIdx.x;
    const int atom0 = blockIdx.x * 16;
    if (t < 48) {
        int gi = atom0 * 3 + t;
        float v = xin[gi];
        x[gi] = v - floorf(v);
        traj[gi] = 0.f;
    }
    {
        const int r = t >> 4;
        const int f0 = (t & 15) * 8;
        const int a = atom0 + r;
        const float4* src = (const float4*)(emb + z[a] * FD + f0);
        float4 v0 = src[0], v1 = src[1];
        float4* dst = (float4*)(h + a * FD + f0);
        dst[0] = v0; dst[1] = v1;
        float vv[8] = {v0.x, v0.y, v0.z, v0.w, v1.x, v1.y, v1.z, v1.w};
        short8 shv, slv;
#pragma unroll
        for (int i = 0; i < 8; ++i) {
            short hi = f2b(vv[i]);
            shv[i] = hi; slv[i] = f2b(vv[i] - b2f(hi));
        }
        *(short8*)&sAH[r * 136 + f0] = shv;
        *(short8*)&sAL[r * 136 + f0] = slv;
    }
    __syncthreads();
    const int w = t >> 6, lane = t & 63, quad = lane >> 4, col = lane & 15;
    const int n0 = w * 32;
    f32x4 acc0 = {0.f, 0.f, 0.f, 0.f}, acc1 = {0.f, 0.f, 0.f, 0.f};
#pragma unroll
    for (int ks = 0; ks < 4; ++ks) {
        short8 ah = *(const short8*)&sAH[col * 136 + ks * 32 + quad * 8];
        short8 al = *(const short8*)&sAL[col * 136 + ks * 32 + quad * 8];
        short8 bh0 = ldb(W1h, n0 + col, ks, quad);
        short8 bl0 = ldb(W1l, n0 + col, ks, quad);
        short8 bh1 = ldb(W1h, n0 + 16 + col, ks, quad);
        short8 bl1 = ldb(W1l, n0 + 16 + col, ks, quad);
        acc0 = __builtin_amdgcn_mfma_f32_16x16x32_bf16(ah, bh0, acc0, 0, 0, 0);
        acc0 = __builtin_amdgcn_mfma_f32_16x16x32_bf16(ah, bl0, acc0, 0, 0, 0);
        acc0 = __builtin_amdgcn_mfma_f32_16x16x32_bf16(al, bh0, acc0, 0, 0, 0);
        acc1 = __builtin_amdgcn_mfma_f32_16x16x32_bf16(ah, bh1, acc1, 0, 0, 0);
        acc1 = __builtin_amdgcn_mfma_f32_16x16x32_bf16(ah, bl1, acc1, 0, 0, 0);
        acc1 = __builtin_amdgcn_mfma_f32_16x16x32_bf16(al, bh1, acc1, 0, 0, 0);
    }
#pragma unroll
    for (int nt = 0; nt < 2; ++nt) {
        int gn = n0 + nt * 16 + col;
        f32x4 av = (nt == 0) ? acc0 : acc1;
#pragma unroll
        for (int r = 0; r < 4; ++r)
            hW[(atom0 + quad * 4 + r) * FD + gn] = av[r];
    }
}

// ---------------- fused layer (split-MFMA): [knn] + dist + agg + W2 GEMM + residual (+pq) + next W1 ----------------
// grid 512 x 256; block = 8 atoms. mode_knn: compute knn in-block and emit idx/u0/dist0.
__global__ __launch_bounds__(256, 2) void layer_kernel(
    const float* __restrict__ hW, int* __restrict__ idxb,
    float* __restrict__ dist0, float* __restrict__ u0w,
    const float* __restrict__ x, const float* __restrict__ geo,
    int mode_knn, int use_d0, int use_geo,
    const float* __restrict__ wl, const float* __restrict__ b1,
    const short* __restrict__ W2h, const short* __restrict__ W2l,
    const float* __restrict__ b2,
    const short* __restrict__ W1nh, const short* __restrict__ W1nl,
    float* __restrict__ hWout,
    float* __restrict__ h, int write_h,
    const float* __restrict__ we_a, const float* __restrict__ we_p,
    float* __restrict__ p, float* __restrict__ q)
{
    __shared__ short sAggH[16 * 136]; // agg bf16 hi [m][k] (rows 8-15 unused)
    __shared__ short sAggL[16 * 136]; // agg bf16 lo
    __shared__ short sHnH[16 * 136];  // h_new bf16 hi
    __shared__ short sHnL[16 * 136];  // h_new bf16 lo
    __shared__ float sHf[8 * 136];    // h_new fp32 (for p,q)
    __shared__ int   sIdx[8 * KNN];
    __shared__ float sDist[8 * KNN];
    const int t = threadIdx.x;
    const int atom0 = blockIdx.x * 8;
    const int w = t >> 6, lane = t & 63, quad = lane >> 4, col = lane & 15;
    const int n0 = w * 32;
    // phase 1: indices + distances
    if (mode_knn) {
        // knn for own 8 atoms: 4 waves x 2 atoms (identity cell)
        for (int rep = 0; rep < 2; ++rep) {
            const int slot = w * 2 + rep;
            const int a = atom0 + slot;
            const int bS = a >> 8;
            const float xi0 = x[a * 3 + 0], xi1 = x[a * 3 + 1], xi2 = x[a * 3 + 2];
            unsigned long long key[4];
#pragma unroll
            for (int tt = 0; tt < 4; ++tt) {
                int jg = bS * NATS + lane + tt * 64;
                float d0 = x[jg * 3 + 0] - xi0; d0 -= rintf(d0);
                float d1 = x[jg * 3 + 1] - xi1; d1 -= rintf(d1);
                float d2 = x[jg * 3 + 2] - xi2; d2 -= rintf(d2);
                float dd = sqrtf(d0 * d0 + d1 * d1 + d2 * d2);
                if (jg == a) dd += 1e6f;        // exclude self (ref adds 1e6*eye)
                key[tt] = ((unsigned long long)__float_as_uint(dd) << 32) | (unsigned)jg;
            }
            int myj = 0;
            for (int sel = 0; sel < KNN; ++sel) {
                unsigned long long m = key[0];
                if (key[1] < m) m = key[1];
                if (key[2] < m) m = key[2];
                if (key[3] < m) m = key[3];
#pragma unroll
                for (int off = 32; off > 0; off >>= 1) {
                    unsigned lo = (unsigned)__shfl_xor((int)(unsigned)(m & 0xffffffffu), off);
                    unsigned hi = (unsigned)__shfl_xor((int)(unsigned)(m >> 32), off);
                    unsigned long long o = ((unsigned long long)hi << 32) | lo;
                    if (o < m) m = o;
                }
                int jw = (int)(m & 0xffffffffu);
                if (lane == 0) idxb[a * KNN + sel] = jw;
                if (lane == sel) myj = jw;
#pragma unroll
                for (int tt = 0; tt < 4; ++tt) if (key[tt] == m) key[tt] = ~0ull;
            }
            if (lane < KNN) {
                float f0 = x[myj * 3 + 0] - xi0; f0 -= rintf(f0);
                float f1 = x[myj * 3 + 1] - xi1; f1 -= rintf(f1);
                float f2 = x[myj * 3 + 2] - xi2; f2 -= rintf(f2);
                float dd = sqrtf(f0 * f0 + f1 * f1 + f2 * f2);
                float inv = fast_rcp(dd + 1e-12f);
                int e = a * KNN + lane;
                u0w[e * 3 + 0] = f0 * inv; u0w[e * 3 + 1] = f1 * inv; u0w[e * 3 + 2] = f2 * inv;
                dist0[e] = dd;
                sIdx[slot * KNN + lane] = myj;
                sDist[slot * KNN + lane] = dd;
            }
        }
    } else if (t < 8 * KNN) {
        int a = atom0 + (t / KNN);
        int j = idxb[atom0 * KNN + t];
        sIdx[t] = j;
        float d;
        if (use_d0) {
            d = dist0[atom0 * KNN + t];
        } else {
            float f0 = x[j * 3 + 0] - x[a * 3 + 0]; f0 -= rintf(f0);
            float f1 = x[j * 3 + 1] - x[a * 3 + 1]; f1 -= rintf(f1);
            float f2 = x[j * 3 + 2] - x[a * 3 + 2]; f2 -= rintf(f2);
            float v0 = f0, v1 = f1, v2 = f2;
            if (use_geo) {
                const float* c = geo + (a >> 8) * 9;
                v0 = f0 * c[0] + f1 * c[3] + f2 * c[6];
                v1 = f0 * c[1] + f1 * c[4] + f2 * c[7];
                v2 = f0 * c[2] + f1 * c[5] + f2 * c[8];
            }
            d = sqrtf(v0 * v0 + v1 * v1 + v2 * v2);
        }
        sDist[t] = d;
    }
    __syncthreads();
    // phase 2: agg s_a[g] = sum_k silu(hW[j][g] + d*wl[g] + b1[g]) -> bf16 hi/lo
    {
        const int g = t & 127;
        const int sub = t >> 7;
        const float wlg = wl[g];
        const float b1g = b1[g];
#pragma unroll
        for (int rep = 0; rep < 4; ++rep) {
            const int a = rep * 2 + sub;
            float s = 0.f;
#pragma unroll 8
            for (int k = 0; k < KNN; ++k) {
                int j = sIdx[a * KNN + k];
                float v = hW[j * FD + g] + sDist[a * KNN + k] * wlg + b1g;
                s += silu_f(v);
            }
            short hi = f2b(s);
            sAggH[a * 136 + g] = hi;
            sAggL[a * 136 + g] = f2b(s - b2f(hi));
        }
    }
    __syncthreads();
    // phase 3: W2 split-MFMA GEMM (b-frags straight from global)
    f32x4 acc0 = {0.f, 0.f, 0.f, 0.f}, acc1 = {0.f, 0.f, 0.f, 0.f};
#pragma unroll
    for (int ks = 0; ks < 4; ++ks) {
        short8 ah = *(const short8*)&sAggH[col * 136 + ks * 32 + quad * 8];
        short8 al = *(const short8*)&sAggL[col * 136 + ks * 32 + quad * 8];
        short8 bh0 = ldb(W2h, n0 + col, ks, quad);
        short8 bl0 = ldb(W2l, n0 + col, ks, quad);
        short8 bh1 = ldb(W2h, n0 + 16 + col, ks, quad);
        short8 bl1 = ldb(W2l, n0 + 16 + col, ks, quad);
        acc0 = __builtin_amdgcn_mfma_f32_16x16x32_bf16(ah, bh0, acc0, 0, 0, 0);
        acc0 = __builtin_amdgcn_mfma_f32_16x16x32_bf16(ah, bl0, acc0, 0, 0, 0);
        acc0 = __builtin_amdgcn_mfma_f32_16x16x32_bf16(al, bh0, acc0, 0, 0, 0);
        acc1 = __builtin_amdgcn_mfma_f32_16x16x32_bf16(ah, bh1, acc1, 0, 0, 0);
        acc1 = __builtin_amdgcn_mfma_f32_16x16x32_bf16(ah, bl1, acc1, 0, 0, 0);
        acc1 = __builtin_amdgcn_mfma_f32_16x16x32_bf16(al, bh1, acc1, 0, 0, 0);
    }
    // epilogue: residual + silu; write h (optional); sHn hi/lo + sHf fp32
#pragma unroll
    for (int nt = 0; nt < 2; ++nt) {
        int gn = n0 + nt * 16 + col;
        float bb = b2[gn];
        f32x4 av = (nt == 0) ? acc0 : acc1;
#pragma unroll
        for (int r = 0; r < 4; ++r) {
            int row = quad * 4 + r;
            if (row < 8) {
                float o = h[(atom0 + row) * FD + gn] + silu_f(av[r] + bb);
                if (write_h) h[(atom0 + row) * FD + gn] = o;
                short hi = f2b(o);
                sHnH[row * 136 + gn] = hi;
                sHnL[row * 136 + gn] = f2b(o - b2f(hi));
                sHf[row * 136 + gn] = o;
            }
        }
    }
    __syncthreads();
    // phase 4: p,q epilogue (action layers) from fp32 h_new
    if (we_a != nullptr && t < 128) {
        int a = t >> 4, gr = t & 15;
        float pp = 0.f, qq = 0.f;
#pragma unroll
        for (int i = 0; i < 8; ++i) {
            int g = gr + i * 16;
            float hv = sHf[a * 136 + g];
            pp += hv * we_a[g];
            qq += hv * we_p[g];
        }
#pragma unroll
        for (int off = 8; off >= 1; off >>= 1) {
            pp += __shfl_xor(pp, off);
            qq += __shfl_xor(qq, off);
        }
        if (gr == 0) { p[atom0 + a] = pp; q[atom0 + a] = qq; }
    }
    // phase 5: next-layer W1 split-MFMA GEMM on h_new
    if (W1nh != nullptr) {
        f32x4 d0 = {0.f, 0.f, 0.f, 0.f}, d1 = {0.f, 0.f, 0.f, 0.f};
#pragma unroll
        for (int ks = 0; ks < 4; ++ks) {
            short8 ah = *(const short8*)&sHnH[col * 136 + ks * 32 + quad * 8];
            short8 al = *(const short8*)&sHnL[col * 136 + ks * 32 + quad * 8];
            short8 bh0 = ldb(W1nh, n0 + col, ks, quad);
            short8 bl0 = ldb(W1nl, n0 + col, ks, quad);
            short8 bh1 = ldb(W1nh, n0 + 16 + col, ks, quad);
            short8 bl1 = ldb(W1nl, n0 + 16 + col, ks, quad);
            d0 = __builtin_amdgcn_mfma_f32_16x16x32_bf16(ah, bh0, d0, 0, 0, 0);
            d0 = __builtin_amdgcn_mfma_f32_16x16x32_bf16(ah, bl0, d0, 0, 0, 0);
            d0 = __builtin_amdgcn_mfma_f32_16x16x32_bf16(al, bh0, d0, 0, 0, 0);
            d1 = __builtin_amdgcn_mfma_f32_16x16x32_bf16(ah, bh1, d1, 0, 0, 0);
            d1 = __builtin_amdgcn_mfma_f32_16x16x32_bf16(ah, bl1, d1, 0, 0, 0);
            d1 = __builtin_amdgcn_mfma_f32_16x16x32_bf16(al, bh1, d1, 0, 0, 0);
        }
#pragma unroll
        for (int nt = 0; nt < 2; ++nt) {
            int gn = n0 + nt * 16 + col;
            f32x4 av = (nt == 0) ? d0 : d1;
#pragma unroll
            for (int r = 0; r < 4; ++r) {
                int row = quad * 4 + r;
                if (row < 8)
                    hWout[(atom0 + row) * FD + gn] = av[r];
            }
        }
    }
}

// ---------------- per-atom action accumulation (inline vec/u): partials + x_cart ----------------
__global__ __launch_bounds__(256) void accum_kernel(
    const float* __restrict__ p, const float* __restrict__ q,
    const int* __restrict__ idxb, const float* __restrict__ x,
    const float* __restrict__ geo, int use_geo,
    const float* __restrict__ u0b,
    float* __restrict__ part, float* __restrict__ xcart)
{
    const int blk = blockIdx.x;
    const int t = threadIdx.x;
    const int w = t >> 6;
    const int lane = t & 63;
    const int a = blk * 4 + w;
    const int b = a >> 8;
    __shared__ float swe[4][KNN], swp[4][KNN];
    __shared__ float su[4][KNN][3], su0[4][KNN][3], sv[4][KNN][3];
    __shared__ float spart[4][18];
    if (lane < KNN) {
        int e = a * KNN + lane;
        int j = idxb[e];
        swe[w][lane] = tanh_f(p[a] + p[j]);
        swp[w][lane] = tanh_f(q[a] + q[j]);
        float f0 = x[j * 3 + 0] - x[a * 3 + 0]; f0 -= rintf(f0);
        float f1 = x[j * 3 + 1] - x[a * 3 + 1]; f1 -= rintf(f1);
        float f2 = x[j * 3 + 2] - x[a * 3 + 2]; f2 -= rintf(f2);
        float v0 = f0, v1 = f1, v2 = f2;
        if (use_geo) {
            const float* c = geo + b * 9;
            v0 = f0 * c[0] + f1 * c[3] + f2 * c[6];
            v1 = f0 * c[1] + f1 * c[4] + f2 * c[7];
            v2 = f0 * c[2] + f1 * c[5] + f2 * c[8];
        }
        float dd = sqrtf(v0 * v0 + v1 * v1 + v2 * v2);
        float inv = fast_rcp(dd + 1e-12f);
        sv[w][lane][0] = v0; sv[w][lane][1] = v1; sv[w][lane][2] = v2;
        su[w][lane][0] = v0 * inv; su[w][lane][1] = v1 * inv; su[w][lane][2] = v2 * inv;
        su0[w][lane][0] = u0b[e * 3]; su0[w][lane][1] = u0b[e * 3 + 1]; su0[w][lane][2] = u0b[e * 3 + 2];
    }
    __syncthreads();
    float r[21];
#pragma unroll
    for (int i = 0; i < 21; ++i) r[i] = 0.f;
    if (lane < KNN) {
        float wgt = swe[w][lane];
        float ux = su[w][lane][0], uy = su[w][lane][1], uz = su[w][lane][2];
        r[0] = wgt * ux * ux; r[1] = wgt * ux * uy; r[2] = wgt * ux * uz;
        r[3] = wgt * uy * ux; r[4] = wgt * uy * uy; r[5] = wgt * uy * uz;
        r[6] = wgt * uz * ux; r[7] = wgt * uz * uy; r[8] = wgt * uz * uz;
        float wp = swp[w][lane];
        r[18] = wp * sv[w][lane][0]; r[19] = wp * sv[w][lane][1]; r[20] = wp * sv[w][lane][2];
    }
#pragma unroll
    for (int tt = 0; tt < 9; ++tt) {
        int pr = lane + (tt << 6);          // 0..575 = 24*24
        int j = pr / KNN, k = pr - j * KNN;
        float c0x = su0[w][j][1] * su0[w][k][2] - su0[w][j][2] * su0[w][k][1];
        float c0y = su0[w][j][2] * su0[w][k][0] - su0[w][j][0] * su0[w][k][2];
        float c0z = su0[w][j][0] * su0[w][k][1] - su0[w][j][1] * su0[w][k][0];
        float nn2 = c0x * c0x + c0y * c0y + c0z * c0z;
        if (nn2 > 1e-6f) {
            float cx = su[w][j][1] * su[w][k][2] - su[w][j][2] * su[w][k][1];
            float cy = su[w][j][2] * su[w][k][0] - su[w][j][0] * su[w][k][2];
            float cz = su[w][j][0] * su[w][k][1] - su[w][j][1] * su[w][k][0];
            float wt = swe[w][j] * swe[w][k];
            r[9]  += wt * cx * cx; r[10] += wt * cx * cy; r[11] += wt * cx * cz;
            r[12] += wt * cy * cx; r[13] += wt * cy * cy; r[14] += wt * cy * cz;
            r[15] += wt * cz * cx; r[16] += wt * cz * cy; r[17] += wt * cz * cz;
        }
    }
#pragma unroll
    for (int off = 32; off > 0; off >>= 1)
#pragma unroll
        for (int i = 0; i < 21; ++i) r[i] += __shfl_down(r[i], off);
    if (lane == 0) {
#pragma unroll
        for (int i = 0; i < 18; ++i) spart[w][i] = r[i];
        xcart[a * 3 + 0] = EPSA * r[18];
        xcart[a * 3 + 1] = EPSA * r[19];
        xcart[a * 3 + 2] = EPSA * r[20];
    }
    __syncthreads();
    if (t < 18)
        part[blk * 18 + t] = spart[0][t] + spart[1][t] + spart[2][t] + spart[3][t];
}

// ---------------- fused rho + pos ----------------
__global__ __launch_bounds__(256) void rho_pos_kernel(const float* __restrict__ part,
    const float* __restrict__ xcart,
    float* __restrict__ rho, float* __restrict__ geo,
    float* __restrict__ x, float* __restrict__ traj,
    float* __restrict__ out, int first, int last)
{
    const int b = blockIdx.x;
    const int t = threadIdx.x;
    __shared__ float sIV[9];
    if (t < 64) {
        float r[18];
#pragma unroll
        for (int i = 0; i < 18; ++i) r[i] = part[(b * 64 + t) * 18 + i];
#pragma unroll
        for (int off = 32; off > 0; off >>= 1)
#pragma unroll
            for (int i = 0; i < 18; ++i) r[i] += __shfl_down(r[i], off);
        if (t == 0) {
            float A[9];
#pragma unroll
            for (int i = 0; i < 9; ++i) {
                float strain = r[i] / 6144.f;           // NAT*K
                float tri = r[9 + i] / 147456.f;        // NAT*K*K
                A[i] = ((i == 0 || i == 4 || i == 8) ? 1.f : 0.f) + EPSA * (strain + tri);
            }
            float N[9], IV[9];
            if (first) {
#pragma unroll
                for (int i = 0; i < 9; ++i) { N[i] = A[i]; IV[i] = (i == 0 || i == 4 || i == 8) ? 1.f : 0.f; }
            } else {
                float R[9], G[9];
#pragma unroll
                for (int i = 0; i < 9; ++i) { R[i] = rho[b * 9 + i]; G[i] = geo[b * 9 + i]; }
#pragma unroll
                for (int i = 0; i < 3; ++i)
#pragma unroll
                    for (int k = 0; k < 3; ++k)
                        N[i * 3 + k] = A[i * 3] * R[k] + A[i * 3 + 1] * R[3 + k] + A[i * 3 + 2] * R[6 + k];
                float det = G[0] * (G[4] * G[8] - G[5] * G[7])
                          - G[1] * (G[3] * G[8] - G[5] * G[6])
                          + G[2] * (G[3] * G[7] - G[4] * G[6]);
                float id = 1.f / det;
                IV[0] = (G[4] * G[8] - G[5] * G[7]) * id;
                IV[1] = (G[2] * G[7] - G[1] * G[8]) * id;
                IV[2] = (G[1] * G[5] - G[2] * G[4]) * id;
                IV[3] = (G[5] * G[6] - G[3] * G[8]) * id;
                IV[4] = (G[0] * G[8] - G[2] * G[6]) * id;
                IV[5] = (G[2] * G[3] - G[0] * G[5]) * id;
                IV[6] = (G[3] * G[7] - G[4] * G[6]) * id;
                IV[7] = (G[1] * G[6] - G[0] * G[7]) * id;
                IV[8] = (G[0] * G[4] - G[1] * G[3]) * id;
            }
#pragma unroll
            for (int i = 0; i < 9; ++i) {
                sIV[i] = IV[i];
                rho[b * 9 + i] = N[i];
                if (!last) geo[b * 9 + i] = N[i];
                else out[NATOMS * 3 + b * 9 + i] = N[i];
            }
        }
    }
    __syncthreads();
    for (int d = t; d < NATS * 3; d += 256) {
        int al = d / 3, dim = d - al * 3;
        int ga = b * NATS + al;
        int gi = ga * 3 + dim;
        float c0 = xcart[ga * 3 + 0], c1 = xcart[ga * 3 + 1], c2 = xcart[ga * 3 + 2];
        float tj = traj[gi] + xcart[gi];
        if (!last) {
            float xf = c0 * sIV[0 + dim] + c1 * sIV[3 + dim] + c2 * sIV[6 + dim];
            x[gi] += xf;
            traj[gi] = tj;
        } else {
            out[gi] = tj;
        }
    }
}

extern "C" void kernel_launch(void* const* d_in, const int* in_sizes, int n_in,
                              void* d_out, int out_size, void* d_ws, size_t ws_size,
                              hipStream_t stream)
{
    (void)in_sizes; (void)n_in; (void)out_size; (void)ws_size;
    const float* in_x = (const float*)d_in[1];
    const int*   z    = (const int*)d_in[2];
    const float* emb  = (const float*)d_in[4];
    const float* mW1  = (const float*)d_in[5];
    const float* mb1  = (const float*)d_in[6];
    const float* mW2  = (const float*)d_in[7];
    const float* mb2  = (const float*)d_in[8];
    const float* uW1  = (const float*)d_in[9];
    const float* ub1  = (const float*)d_in[10];
    const float* uW2  = (const float*)d_in[11];
    const float* ub2  = (const float*)d_in[12];
    const float* awe  = (const float*)d_in[13];
    const float* pwe  = (const float*)d_in[14];
    float* out = (float*)d_out;

    // workspace carve
    char* wsb = (char*)d_ws;
    size_t off = 0;
    auto carve = [&](size_t elems) {
        void* ptr = wsb + off;
        off += (elems * 4 + 255) & ~(size_t)255;
        return ptr;
    };
    float* traj  = (float*)carve(NATOMS * 3);
    float* part  = (float*)carve(1024 * 18);
    float* x     = (float*)carve(NATOMS * 3);
    float* xcart = (float*)carve(NATOMS * 3);
    float* p     = (float*)carve(NATOMS);
    float* q     = (float*)carve(NATOMS);
    float* rho   = (float*)carve(NB * 9);
    float* geo   = (float*)carve(NB * 9);
    float* u0    = (float*)carve(NEDGE * 3);
    float* dist0 = (float*)carve(NEDGE);
    float* h     = (float*)carve(NATOMS * FD);
    float* hWa   = (float*)carve(NATOMS * FD);
    float* hWb   = (float*)carve(NATOMS * FD);
    int*   idx   = (int*)carve(NEDGE);
    short* wth   = (short*)carve(16 * 16384 / 2);   // 16 bf16 hi matrices [n][k]
    short* wtl   = (short*)carve(16 * 16384 / 2);   // 16 bf16 lo matrices [n][k]

    auto WH = [&](int m) { return wth + m * 16384; };
    auto WL = [&](int m) { return wtl + m * 16384; };
    // m: 0-3 mpnn W1, 4-7 mpnn W2, 8-11 upd W1, 12-15 upd W2

    prep_kernel<<<1024, 256, 0, stream>>>(mW1, mW2, uW1, uW2, wth, wtl);
    init_kernel<<<256, 256, 0, stream>>>(in_x, z, emb, WH(0), WL(0), x, traj, h, hWa);

    float* hw_in = hWa;
    float* hw_out = hWb;

    // message-passing layers (identity geometry; layer 0 computes knn in-block)
    for (int l = 0; l < 4; ++l) {
        int w1n = (l < 3) ? (l + 1) : 8;
        layer_kernel<<<512, 256, 0, stream>>>(hw_in, idx, dist0, u0, x, geo,
            (l == 0) ? 1 : 0, (l == 0) ? 0 : 1, 0,
            mW1 + l * 129 * 128 + 128 * 128, mb1 + l * 128,
            WH(4 + l), WL(4 + l), mb2 + l * 128,
            WH(w1n), WL(w1n), hw_out, h, 1,
            nullptr, nullptr, nullptr, nullptr);
        float* tmp = hw_in; hw_in = hw_out; hw_out = tmp;
    }
    // action layers
    for (int l = 0; l < 4; ++l) {
        const short* W1nh = (l < 3) ? WH(9 + l) : nullptr;
        const short* W1nl = (l < 3) ? WL(9 + l) : nullptr;
        layer_kernel<<<512, 256, 0, stream>>>(hw_in, idx, dist0, u0, x, geo,
            0, (l == 0) ? 1 : 0, (l > 0) ? 1 : 0,
            uW1 + l * 129 * 128 + 128 * 128, ub1 + l * 128,
            WH(12 + l), WL(12 + l), ub2 + l * 128,
            W1nh, W1nl, hw_out, h, (l < 3) ? 1 : 0,
            awe + l * 128, pwe + l * 128, p, q);
        float* tmp = hw_in; hw_in = hw_out; hw_out = tmp;
        accum_kernel<<<1024, 256, 0, stream>>>(p, q, idx, x, geo, (l > 0) ? 1 : 0,
            u0, part, xcart);
        rho_pos_kernel<<<NB, 256, 0, stream>>>(part, xcart, rho, geo, x, traj, out,
            (l == 0) ? 1 : 0, (l == 3) ? 1 : 0);
    }
}